// Round 3
// baseline (127.791 us; speedup 1.0000x reference)
//
#include <hip/hip_runtime.h>

#define BB 32
#define NN 2048
#define DD 65
#define HH 64
#define ST 68                // padded leading dim (16B-aligned float4 frags)
#define TILE (DD * ST)       // 4420 floats per padded 65x65 matrix
#define CC 32                // x chunks per batch (64 rows each)

__device__ __forceinline__ float4 f4add(float4 a, float4 b) {
  return make_float4(a.x + b.x, a.y + b.y, a.z + b.z, a.w + b.w);
}

// async global->LDS, 16B per lane, wave-uniform LDS base + lane*16
#define GL2LDS(g, l)                                             \
  __builtin_amdgcn_global_load_lds(                              \
      (const __attribute__((address_space(1))) void*)(g),        \
      (__attribute__((address_space(3))) void*)(l), 16, 0, 0)

// ---------------------------------------------------------------------------
// k1: partial Gram P[chunk] = Xc^T Xc for a 64-row chunk, 8x8 register tile,
// ONE WAVE PER CHUNK. 512 blocks x 128 threads (2 waves, 2 chunks); LDS slice
// is wave-private -> no __syncthreads at all. 8x8 regs give 64 FMA per 16
// LDS-floats (1 MAC/B, 2x the old 4x4 ratio) -> VALU/LDS balanced ~5us.
// Col/row-64 edge via f64[] (all lanes compute, ty8==0 stores + mirrors).
// ---------------------------------------------------------------------------
__global__ __launch_bounds__(128, 2) void k1_gram(const float* __restrict__ x,
                                                  float* __restrict__ P) {
  __shared__ __align__(16) float Xl[2][64 * ST];
  const int t = (int)threadIdx.x;
  const int w = t >> 6, lane = t & 63;
  const int tx8 = lane & 7, ty8 = lane >> 3;
  const int chunk = (int)blockIdx.x * 2 + w;       // 0..1023
  const int b = chunk >> 5, c = chunk & 31;
  const float4* src4 =
      (const float4*)(x + ((size_t)b * NN + (size_t)c * 64) * DD);
  float* Xw = Xl[w];

  // wave-local staging: 1040 float4 -> padded [64][ST]; 2 passes (9+8)
#pragma unroll
  for (int p = 0; p < 2; p++) {
    float4 tmp[9];
    const int cnt = p ? 8 : 9;
#pragma unroll
    for (int q = 0; q < 9; q++) {
      const int i4 = lane + 64 * (9 * p + q);
      if (q < cnt && i4 < 1040) tmp[q] = src4[i4];
    }
#pragma unroll
    for (int q = 0; q < 9; q++) {
      const int i4 = lane + 64 * (9 * p + q);
      if (q < cnt && i4 < 1040) {
        const int f = 4 * i4;
        const float vv[4] = {tmp[q].x, tmp[q].y, tmp[q].z, tmp[q].w};
#pragma unroll
        for (int j = 0; j < 4; j++) {
          const int r = (f + j) / DD, cc = (f + j) - r * DD;
          Xw[r * ST + cc] = vv[j];
        }
      }
    }
  }
  // no barrier: this wave wrote Xw, this wave reads it (lgkmcnt ordering)

  float g[8][8] = {};
  float f64[8] = {};
  float gcc = 0.f;
  for (int n = 0; n < 64; n++) {
    float rowf[8], colf[8];
    *(float4*)&rowf[0] = *(const float4*)&Xw[n * ST + 8 * ty8];
    *(float4*)&rowf[4] = *(const float4*)&Xw[n * ST + 8 * ty8 + 4];
    *(float4*)&colf[0] = *(const float4*)&Xw[n * ST + 8 * tx8];
    *(float4*)&colf[4] = *(const float4*)&Xw[n * ST + 8 * tx8 + 4];
    const float x64 = Xw[n * ST + 64];  // broadcast
#pragma unroll
    for (int r = 0; r < 8; r++)
#pragma unroll
      for (int cc = 0; cc < 8; cc++)
        g[r][cc] = fmaf(rowf[r], colf[cc], g[r][cc]);
#pragma unroll
    for (int cc = 0; cc < 8; cc++) f64[cc] = fmaf(x64, colf[cc], f64[cc]);
    gcc = fmaf(x64, x64, gcc);
  }

  float* Pp = P + (size_t)chunk * TILE;
#pragma unroll
  for (int r = 0; r < 8; r++) {
    *(float4*)&Pp[(8 * ty8 + r) * ST + 8 * tx8] = *(float4*)&g[r][0];
    *(float4*)&Pp[(8 * ty8 + r) * ST + 8 * tx8 + 4] = *(float4*)&g[r][4];
  }
  if (ty8 == 0) {
#pragma unroll
    for (int cc = 0; cc < 8; cc++) {
      Pp[64 * ST + 8 * tx8 + cc] = f64[cc];          // G[64][j]
      Pp[(8 * tx8 + cc) * ST + 64] = f64[cc];        // G[j][64] by symmetry
    }
    if (tx8 == 0) Pp[64 * ST + 64] = gcc;
  }
}

// ---------------------------------------------------------------------------
// kred: G[b] = sum over 32 chunk tiles of P[b]. 160 blocks (5 per batch),
// one float4 slot per thread, 8 loads in flight + tree sum (x4 groups).
// ---------------------------------------------------------------------------
__global__ __launch_bounds__(256) void kred(const float* __restrict__ P,
                                            float* __restrict__ G) {
  const int t = (int)threadIdx.x;
  const int blk = (int)blockIdx.x;
  const int b = blk / 5, s = blk - b * 5;
  const int Q = TILE / 4;  // 1105
  const int i4 = s * 256 + t;
  if (i4 < Q) {
    const float4* Pb = (const float4*)(P + (size_t)b * CC * TILE);
    float4 acc = make_float4(0.f, 0.f, 0.f, 0.f);
#pragma unroll
    for (int grp = 0; grp < 4; grp++) {
      float4 v[8];
#pragma unroll
      for (int cc = 0; cc < 8; cc++)
        v[cc] = Pb[(size_t)(8 * grp + cc) * Q + i4];
#pragma unroll
      for (int stp = 4; stp >= 1; stp >>= 1)
#pragma unroll
        for (int cc = 0; cc < stp; cc++) v[cc] = f4add(v[cc], v[cc + stp]);
      acc = f4add(acc, v[0]);
    }
    ((float4*)(G + (size_t)b * TILE))[i4] = acc;
  }
}

// ---------------------------------------------------------------------------
// k2b: ROW-PARALLEL chain. T[i,:] = M[i,:] G Wv^T with M = Wq^T Wk.
// 288 blocks (9 row-groups x 32 batches); unchanged.
// ---------------------------------------------------------------------------
__global__ __launch_bounds__(256) void k2_chain(
    const float* __restrict__ Wq, const float* __restrict__ Wk,
    const float* __restrict__ Wv, const float* __restrict__ G,
    float* __restrict__ Tm) {
  __shared__ __align__(16) float WqL[HH * ST];
  __shared__ __align__(16) float WkL[HH * ST];
  __shared__ __align__(16) float GL[TILE];
  __shared__ __align__(16) float WvT[TILE];
  __shared__ __align__(16) float Mr[8 * ST];
  __shared__ __align__(16) float Rr[8 * ST];

  const int t = (int)threadIdx.x;
  const int tx = t & 31, ty = t >> 5;
  const int blk = (int)blockIdx.x;
  const int b = blk / 9, rg = blk - b * 9;
  const int i = 8 * rg + ty;
  const bool alive = (i < DD);
  const int ic = alive ? i : 0;

  {
    float tq[17], tk[17];
#pragma unroll
    for (int q = 0; q < 17; q++) {
      const int idx = t + 256 * q;
      if (idx < HH * DD) { tq[q] = Wq[idx]; tk[q] = Wk[idx]; }
    }
#pragma unroll
    for (int q = 0; q < 17; q++) {
      const int idx = t + 256 * q;
      if (idx < HH * DD) {
        const int r = idx / DD, cc = idx - r * DD;
        WqL[r * ST + cc] = tq[q];
        WkL[r * ST + cc] = tk[q];
      }
    }
  }
  {
    const float4* Gb4 = (const float4*)(G + (size_t)b * TILE);
    float4 tG[5];
#pragma unroll
    for (int q = 0; q < 5; q++) {
      const int i4 = t + 256 * q;
      if (i4 < TILE / 4) tG[q] = Gb4[i4];
    }
#pragma unroll
    for (int q = 0; q < 5; q++) {
      const int i4 = t + 256 * q;
      if (i4 < TILE / 4) *((float4*)GL + i4) = tG[q];
    }
  }
  {
    float tv[17];
#pragma unroll
    for (int q = 0; q < 17; q++) {
      const int idx = t + 256 * q;
      if (idx < DD * DD) tv[q] = Wv[idx];
    }
#pragma unroll
    for (int q = 0; q < 17; q++) {
      const int idx = t + 256 * q;
      if (idx < DD * DD) {
        const int j = idx / DD, k = idx - j * DD;
        WvT[k * ST + j] = tv[q];
      }
    }
  }
  __syncthreads();

  {
    float m0 = 0.f, m1 = 0.f, m2 = 0.f;
    for (int h = 0; h < HH; h++) {
      const float wq = WqL[h * ST + ic];
      m0 = fmaf(wq, WkL[h * ST + tx], m0);
      m1 = fmaf(wq, WkL[h * ST + tx + 32], m1);
      m2 = fmaf(wq, WkL[h * ST + 64], m2);
    }
    if (alive) {
      Mr[ty * ST + tx] = m0;
      Mr[ty * ST + tx + 32] = m1;
      if (tx == 0) Mr[ty * ST + 64] = m2;
    }
  }
  __syncthreads();

  {
    float r0 = 0.f, r1 = 0.f, r2 = 0.f;
    for (int k = 0; k < DD; k++) {
      const float mm = Mr[ty * ST + k];
      r0 = fmaf(mm, GL[k * ST + tx], r0);
      r1 = fmaf(mm, GL[k * ST + tx + 32], r1);
      r2 = fmaf(mm, GL[k * ST + 64], r2);
    }
    if (alive) {
      Rr[ty * ST + tx] = r0;
      Rr[ty * ST + tx + 32] = r1;
      if (tx == 0) Rr[ty * ST + 64] = r2;
    }
  }
  __syncthreads();

  {
    float t0 = 0.f, t1 = 0.f, t2 = 0.f;
    for (int k = 0; k < DD; k++) {
      const float rv = Rr[ty * ST + k];
      t0 = fmaf(rv, WvT[k * ST + tx], t0);
      t1 = fmaf(rv, WvT[k * ST + tx + 32], t1);
      t2 = fmaf(rv, WvT[k * ST + 64], t2);
    }
    if (alive) {
      float* Tb = Tm + (size_t)b * TILE + (size_t)i * ST;
      Tb[tx] = t0;
      Tb[tx + 32] = t1;
      if (tx == 0) Tb[64] = t2;
    }
  }
}

// ---------------------------------------------------------------------------
// k3: out[chunk] = Xc @ T[b]. ONE WAVE PER CHUNK, 8x8 register tile.
// 512 blocks x 128 threads; the 2 waves share an async-staged Tl (one
// barrier), each owns its Xl slice. Epilogue repacks o[8][8] into the own
// (now-dead) Xl slice as [64][65] and copies out as coalesced float4 --
// wave-local, no second barrier.
// ---------------------------------------------------------------------------
__global__ __launch_bounds__(128, 2) void k3_out(const float* __restrict__ x,
                                                 const float* __restrict__ Tt,
                                                 float* __restrict__ out) {
  __shared__ __align__(16) float Tl[TILE];
  __shared__ __align__(16) float Xl[2][64 * ST];
  const int t = (int)threadIdx.x;
  const int w = t >> 6, lane = t & 63;
  const int tx8 = lane & 7, ty8 = lane >> 3;
  const int blk = (int)blockIdx.x;     // 512
  const int b = blk >> 4;
  const int chunk = (blk & 15) * 2 + w;  // 0..31 within batch
  const float4* Tg4 = (const float4*)(Tt + (size_t)b * TILE);
  const float4* src4 =
      (const float4*)(x + ((size_t)b * NN + (size_t)chunk * 64) * DD);
  float* Xw = Xl[w];

  // async stage T -> Tl (1105 float4): 8 full rounds of 128 + tail of 81
#pragma unroll
  for (int q = 0; q < 8; q++)
    GL2LDS(Tg4 + q * 128 + w * 64 + lane,
           Tl + (size_t)(q * 128 + w * 64) * 4);
  {
    const int s = 1024 + w * 64 + lane;
    if (s < TILE / 4) GL2LDS(Tg4 + s, Tl + (size_t)(1024 + w * 64) * 4);
  }

  // wave-local reg-stage of own x chunk (2 passes, 9+8)
#pragma unroll
  for (int p = 0; p < 2; p++) {
    float4 tmp[9];
    const int cnt = p ? 8 : 9;
#pragma unroll
    for (int q = 0; q < 9; q++) {
      const int i4 = lane + 64 * (9 * p + q);
      if (q < cnt && i4 < 1040) tmp[q] = src4[i4];
    }
#pragma unroll
    for (int q = 0; q < 9; q++) {
      const int i4 = lane + 64 * (9 * p + q);
      if (q < cnt && i4 < 1040) {
        const int f = 4 * i4;
        const float vv[4] = {tmp[q].x, tmp[q].y, tmp[q].z, tmp[q].w};
#pragma unroll
        for (int j = 0; j < 4; j++) {
          const int r = (f + j) / DD, cc = (f + j) - r * DD;
          Xw[r * ST + cc] = vv[j];
        }
      }
    }
  }
  __syncthreads();  // drains vmcnt (Tl async loads) + lgkmcnt; Tl shared

  float o[8][8] = {}, o64[8] = {};
  for (int kk = 0; kk < 64; kk += 4) {
    float xa[8][4];
#pragma unroll
    for (int r = 0; r < 8; r++)
      *(float4*)xa[r] = *(const float4*)&Xw[(8 * ty8 + r) * ST + kk];
#pragma unroll
    for (int e = 0; e < 4; e++) {
      float tb[8];
      *(float4*)&tb[0] = *(const float4*)&Tl[(kk + e) * ST + 8 * tx8];
      *(float4*)&tb[4] = *(const float4*)&Tl[(kk + e) * ST + 8 * tx8 + 4];
      const float t64 = Tl[(kk + e) * ST + 64];
#pragma unroll
      for (int r = 0; r < 8; r++) {
#pragma unroll
        for (int cc = 0; cc < 8; cc++)
          o[r][cc] = fmaf(xa[r][e], tb[cc], o[r][cc]);
        o64[r] = fmaf(xa[r][e], t64, o64[r]);
      }
    }
  }
  {  // k = 64 tail
    float tb[8];
    *(float4*)&tb[0] = *(const float4*)&Tl[64 * ST + 8 * tx8];
    *(float4*)&tb[4] = *(const float4*)&Tl[64 * ST + 8 * tx8 + 4];
    const float t64 = Tl[64 * ST + 64];
#pragma unroll
    for (int r = 0; r < 8; r++) {
      const float xs = Xw[(8 * ty8 + r) * ST + 64];
#pragma unroll
      for (int cc = 0; cc < 8; cc++)
        o[r][cc] = fmaf(xs, tb[cc], o[r][cc]);
      o64[r] = fmaf(xs, t64, o64[r]);
    }
  }

  // wave-local repack into own Xw as unpadded [64][65], then f4 copy-out
  float* Ow = Xw;
#pragma unroll
  for (int r = 0; r < 8; r++) {
#pragma unroll
    for (int cc = 0; cc < 8; cc++)
      Ow[(8 * ty8 + r) * DD + 8 * tx8 + cc] = o[r][cc];
    if (tx8 == 0) Ow[(8 * ty8 + r) * DD + 64] = o64[r];
  }
  float4* ob4 = (float4*)(out + ((size_t)b * NN + (size_t)chunk * 64) * DD);
#pragma unroll
  for (int q = 0; q < 17; q++) {
    const int i4 = lane + 64 * q;
    if (i4 < 1040) ob4[i4] = ((const float4*)Ow)[i4];
  }
}

extern "C" void kernel_launch(void* const* d_in, const int* in_sizes, int n_in,
                              void* d_out, int out_size, void* d_ws,
                              size_t ws_size, hipStream_t stream) {
  const float* x = (const float*)d_in[0];
  const float* Wq = (const float*)d_in[1];
  const float* Wk = (const float*)d_in[2];
  const float* Wv = (const float*)d_in[3];
  float* out = (float*)d_out;

  float* P = (float*)d_ws;
  float* G = P + (size_t)BB * CC * TILE;
  float* Tm = G + (size_t)BB * TILE;

  k1_gram<<<BB * CC / 2, 128, 0, stream>>>(x, P);
  kred<<<BB * 5, 256, 0, stream>>>(P, G);
  k2_chain<<<BB * 9, 256, 0, stream>>>(Wq, Wk, Wv, G, Tm);
  k3_out<<<BB * CC / 2, 128, 0, stream>>>(x, Tm, out);
  (void)in_sizes; (void)n_in; (void)out_size; (void)ws_size;
}

// Round 4
// 121.357 us; speedup vs baseline: 1.0530x; 1.0530x over previous
//
#include <hip/hip_runtime.h>

#define BB 32
#define NN 2048
#define DD 65
#define HH 64
#define ST 68                // padded leading dim (16B-aligned float4 frags)
#define TILE (DD * ST)       // 4420 floats per padded 65x65 matrix
#define CH 64                // 32-row chunks per batch
#define CROWS 32             // rows per chunk

__device__ __forceinline__ float4 f4add(float4 a, float4 b) {
  return make_float4(a.x + b.x, a.y + b.y, a.z + b.z, a.w + b.w);
}

// async global->LDS, 16B per lane, wave-uniform LDS base + lane*16
#define GL2LDS(g, l)                                             \
  __builtin_amdgcn_global_load_lds(                              \
      (const __attribute__((address_space(1))) void*)(g),        \
      (__attribute__((address_space(3))) void*)(l), 16, 0, 0)

// ---------------------------------------------------------------------------
// k1: partial Gram P[ch] = Xc^T Xc over a 32-ROW chunk, 8x8 register tile,
// one wave per chunk. 2048 chunks -> 2048 waves (2/SIMD TLP; round-3's 1024
// waves = 1/SIMD was the regression). 4 waves/block, wave-private 8.7 KB LDS
// slice (34.8 KB/block); launch_bounds(256,4) caps VGPR at 128 so 4 blocks/CU
// are possible. No __syncthreads (wave-private staging).
// ---------------------------------------------------------------------------
__global__ __launch_bounds__(256, 4) void k1_gram(const float* __restrict__ x,
                                                  float* __restrict__ P) {
  __shared__ __align__(16) float Xl[4][CROWS * ST];
  const int t = (int)threadIdx.x;
  const int w = t >> 6, lane = t & 63;
  const int tx8 = lane & 7, ty8 = lane >> 3;
  const int ch = (int)blockIdx.x * 4 + w;     // 0..2047
  const int b = ch >> 6, c = ch & 63;
  const float4* src4 =
      (const float4*)(x + ((size_t)b * NN + (size_t)c * CROWS) * DD);
  float* Xw = Xl[w];

  {  // stage 520 float4 -> padded [32][ST]; batched loads then scatter
    float4 tmp[9];
#pragma unroll
    for (int q = 0; q < 9; q++) {
      const int i4 = lane + 64 * q;
      if (i4 < 520) tmp[q] = src4[i4];
    }
#pragma unroll
    for (int q = 0; q < 9; q++) {
      const int i4 = lane + 64 * q;
      if (i4 < 520) {
        const int f = 4 * i4;
        const float vv[4] = {tmp[q].x, tmp[q].y, tmp[q].z, tmp[q].w};
#pragma unroll
        for (int j = 0; j < 4; j++) {
          const int r = (f + j) / DD, cc = (f + j) - r * DD;
          Xw[r * ST + cc] = vv[j];
        }
      }
    }
  }
  // no barrier: wave-private slice, in-wave lgkmcnt ordering suffices

  float g[8][8] = {};
  float f64[8] = {};
  float gcc = 0.f;
  for (int n = 0; n < CROWS; n++) {
    float rowf[8], colf[8];
    *(float4*)&rowf[0] = *(const float4*)&Xw[n * ST + 8 * ty8];
    *(float4*)&rowf[4] = *(const float4*)&Xw[n * ST + 8 * ty8 + 4];
    *(float4*)&colf[0] = *(const float4*)&Xw[n * ST + 8 * tx8];
    *(float4*)&colf[4] = *(const float4*)&Xw[n * ST + 8 * tx8 + 4];
    const float x64 = Xw[n * ST + 64];  // broadcast
#pragma unroll
    for (int r = 0; r < 8; r++)
#pragma unroll
      for (int cc = 0; cc < 8; cc++)
        g[r][cc] = fmaf(rowf[r], colf[cc], g[r][cc]);
#pragma unroll
    for (int cc = 0; cc < 8; cc++) f64[cc] = fmaf(x64, colf[cc], f64[cc]);
    gcc = fmaf(x64, x64, gcc);
  }

  float* Pp = P + (size_t)ch * TILE;
#pragma unroll
  for (int r = 0; r < 8; r++) {
    *(float4*)&Pp[(8 * ty8 + r) * ST + 8 * tx8] = *(float4*)&g[r][0];
    *(float4*)&Pp[(8 * ty8 + r) * ST + 8 * tx8 + 4] = *(float4*)&g[r][4];
  }
  if (ty8 == 0) {
#pragma unroll
    for (int cc = 0; cc < 8; cc++) {
      Pp[64 * ST + 8 * tx8 + cc] = f64[cc];          // G[64][j]
      Pp[(8 * tx8 + cc) * ST + 64] = f64[cc];        // G[j][64] by symmetry
    }
    if (tx8 == 0) Pp[64 * ST + 64] = gcc;
  }
}

// ---------------------------------------------------------------------------
// kred: G[b] = sum over 64 chunk tiles of P[b]. 160 blocks (5 per batch),
// one float4 slot per thread, 8 groups x 8 loads in flight + tree sum.
// ---------------------------------------------------------------------------
__global__ __launch_bounds__(256) void kred(const float* __restrict__ P,
                                            float* __restrict__ G) {
  const int t = (int)threadIdx.x;
  const int blk = (int)blockIdx.x;
  const int b = blk / 5, s = blk - b * 5;
  const int Q = TILE / 4;  // 1105
  const int i4 = s * 256 + t;
  if (i4 < Q) {
    const float4* Pb = (const float4*)(P + (size_t)b * CH * TILE);
    float4 acc = make_float4(0.f, 0.f, 0.f, 0.f);
#pragma unroll
    for (int grp = 0; grp < 8; grp++) {
      float4 v[8];
#pragma unroll
      for (int cc = 0; cc < 8; cc++)
        v[cc] = Pb[(size_t)(8 * grp + cc) * Q + i4];
#pragma unroll
      for (int stp = 4; stp >= 1; stp >>= 1)
#pragma unroll
        for (int cc = 0; cc < stp; cc++) v[cc] = f4add(v[cc], v[cc + stp]);
      acc = f4add(acc, v[0]);
    }
    ((float4*)(G + (size_t)b * TILE))[i4] = acc;
  }
}

// ---------------------------------------------------------------------------
// k2b: ROW-PARALLEL chain. T[i,:] = M[i,:] G Wv^T with M = Wq^T Wk.
// 288 blocks (9 row-groups x 32 batches); unchanged.
// ---------------------------------------------------------------------------
__global__ __launch_bounds__(256) void k2_chain(
    const float* __restrict__ Wq, const float* __restrict__ Wk,
    const float* __restrict__ Wv, const float* __restrict__ G,
    float* __restrict__ Tm) {
  __shared__ __align__(16) float WqL[HH * ST];
  __shared__ __align__(16) float WkL[HH * ST];
  __shared__ __align__(16) float GL[TILE];
  __shared__ __align__(16) float WvT[TILE];
  __shared__ __align__(16) float Mr[8 * ST];
  __shared__ __align__(16) float Rr[8 * ST];

  const int t = (int)threadIdx.x;
  const int tx = t & 31, ty = t >> 5;
  const int blk = (int)blockIdx.x;
  const int b = blk / 9, rg = blk - b * 9;
  const int i = 8 * rg + ty;
  const bool alive = (i < DD);
  const int ic = alive ? i : 0;

  {
    float tq[17], tk[17];
#pragma unroll
    for (int q = 0; q < 17; q++) {
      const int idx = t + 256 * q;
      if (idx < HH * DD) { tq[q] = Wq[idx]; tk[q] = Wk[idx]; }
    }
#pragma unroll
    for (int q = 0; q < 17; q++) {
      const int idx = t + 256 * q;
      if (idx < HH * DD) {
        const int r = idx / DD, cc = idx - r * DD;
        WqL[r * ST + cc] = tq[q];
        WkL[r * ST + cc] = tk[q];
      }
    }
  }
  {
    const float4* Gb4 = (const float4*)(G + (size_t)b * TILE);
    float4 tG[5];
#pragma unroll
    for (int q = 0; q < 5; q++) {
      const int i4 = t + 256 * q;
      if (i4 < TILE / 4) tG[q] = Gb4[i4];
    }
#pragma unroll
    for (int q = 0; q < 5; q++) {
      const int i4 = t + 256 * q;
      if (i4 < TILE / 4) *((float4*)GL + i4) = tG[q];
    }
  }
  {
    float tv[17];
#pragma unroll
    for (int q = 0; q < 17; q++) {
      const int idx = t + 256 * q;
      if (idx < DD * DD) tv[q] = Wv[idx];
    }
#pragma unroll
    for (int q = 0; q < 17; q++) {
      const int idx = t + 256 * q;
      if (idx < DD * DD) {
        const int j = idx / DD, k = idx - j * DD;
        WvT[k * ST + j] = tv[q];
      }
    }
  }
  __syncthreads();

  {
    float m0 = 0.f, m1 = 0.f, m2 = 0.f;
    for (int h = 0; h < HH; h++) {
      const float wq = WqL[h * ST + ic];
      m0 = fmaf(wq, WkL[h * ST + tx], m0);
      m1 = fmaf(wq, WkL[h * ST + tx + 32], m1);
      m2 = fmaf(wq, WkL[h * ST + 64], m2);
    }
    if (alive) {
      Mr[ty * ST + tx] = m0;
      Mr[ty * ST + tx + 32] = m1;
      if (tx == 0) Mr[ty * ST + 64] = m2;
    }
  }
  __syncthreads();

  {
    float r0 = 0.f, r1 = 0.f, r2 = 0.f;
    for (int k = 0; k < DD; k++) {
      const float mm = Mr[ty * ST + k];
      r0 = fmaf(mm, GL[k * ST + tx], r0);
      r1 = fmaf(mm, GL[k * ST + tx + 32], r1);
      r2 = fmaf(mm, GL[k * ST + 64], r2);
    }
    if (alive) {
      Rr[ty * ST + tx] = r0;
      Rr[ty * ST + tx + 32] = r1;
      if (tx == 0) Rr[ty * ST + 64] = r2;
    }
  }
  __syncthreads();

  {
    float t0 = 0.f, t1 = 0.f, t2 = 0.f;
    for (int k = 0; k < DD; k++) {
      const float rv = Rr[ty * ST + k];
      t0 = fmaf(rv, WvT[k * ST + tx], t0);
      t1 = fmaf(rv, WvT[k * ST + tx + 32], t1);
      t2 = fmaf(rv, WvT[k * ST + 64], t2);
    }
    if (alive) {
      float* Tb = Tm + (size_t)b * TILE + (size_t)i * ST;
      Tb[tx] = t0;
      Tb[tx + 32] = t1;
      if (tx == 0) Tb[64] = t2;
    }
  }
}

// ---------------------------------------------------------------------------
// k3: out[ch] = Xc @ T[b], one wave per 32-row chunk, o[4][8] per lane.
// X operand read DIRECTLY from global (b32, L1-streaming: each 64B line
// serves 16 consecutive k) -> no Xl, no alignment trap. LDS holds only the
// shared Tl (17.7 KB, async global_load_lds). 512 blocks x 256 thr =
// 2048 waves (2/SIMD); launch_bounds(256,4) caps VGPR at 128.
// ---------------------------------------------------------------------------
__global__ __launch_bounds__(256, 4) void k3_out(const float* __restrict__ x,
                                                 const float* __restrict__ Tt,
                                                 float* __restrict__ out) {
  __shared__ __align__(16) float Tl[TILE];
  const int t = (int)threadIdx.x;
  const int w = t >> 6, lane = t & 63;
  const int tx8 = lane & 7, ry4 = lane >> 3;
  const int blk = (int)blockIdx.x;       // 512
  const int b = blk >> 4;                // 16 blocks per batch
  const int c = (blk & 15) * 4 + w;      // chunk 0..63 within batch
  const float4* Tg4 = (const float4*)(Tt + (size_t)b * TILE);
  const float* xs = x + ((size_t)b * NN + (size_t)c * CROWS) * DD;

  // async stage T -> Tl (1105 float4): 4 rounds of 256 + tail of 81
#pragma unroll
  for (int q = 0; q < 4; q++)
    GL2LDS(Tg4 + q * 256 + w * 64 + lane,
           Tl + (size_t)(q * 256 + w * 64) * 4);
  {
    const int s = 1024 + w * 64 + lane;
    if (s < TILE / 4) GL2LDS(Tg4 + s, Tl + (size_t)(1024 + w * 64) * 4);
  }
  __syncthreads();  // drains vmcnt -> Tl ready

  const float* xr0 = xs + (size_t)(4 * ry4 + 0) * DD;
  const float* xr1 = xs + (size_t)(4 * ry4 + 1) * DD;
  const float* xr2 = xs + (size_t)(4 * ry4 + 2) * DD;
  const float* xr3 = xs + (size_t)(4 * ry4 + 3) * DD;

  float o[4][8] = {}, o64[4] = {};
  for (int kk = 0; kk < 64; kk += 4) {
    float xa[4][4];  // [r][e]: 16 independent b32 loads, batched in flight
#pragma unroll
    for (int e = 0; e < 4; e++) {
      xa[0][e] = xr0[kk + e];
      xa[1][e] = xr1[kk + e];
      xa[2][e] = xr2[kk + e];
      xa[3][e] = xr3[kk + e];
    }
#pragma unroll
    for (int e = 0; e < 4; e++) {
      const int k = kk + e;
      float tb[8];
      *(float4*)&tb[0] = *(const float4*)&Tl[k * ST + 8 * tx8];
      *(float4*)&tb[4] = *(const float4*)&Tl[k * ST + 8 * tx8 + 4];
      const float t64 = Tl[k * ST + 64];
#pragma unroll
      for (int r = 0; r < 4; r++) {
#pragma unroll
        for (int cc = 0; cc < 8; cc++)
          o[r][cc] = fmaf(xa[r][e], tb[cc], o[r][cc]);
        o64[r] = fmaf(xa[r][e], t64, o64[r]);
      }
    }
  }
  {  // k = 64 tail
    float xk[4];
    xk[0] = xr0[64]; xk[1] = xr1[64]; xk[2] = xr2[64]; xk[3] = xr3[64];
    float tb[8];
    *(float4*)&tb[0] = *(const float4*)&Tl[64 * ST + 8 * tx8];
    *(float4*)&tb[4] = *(const float4*)&Tl[64 * ST + 8 * tx8 + 4];
    const float t64 = Tl[64 * ST + 64];
#pragma unroll
    for (int r = 0; r < 4; r++) {
#pragma unroll
      for (int cc = 0; cc < 8; cc++)
        o[r][cc] = fmaf(xk[r], tb[cc], o[r][cc]);
      o64[r] = fmaf(xk[r], t64, o64[r]);
    }
  }

  float* ob = out + ((size_t)b * NN + (size_t)c * CROWS) * DD;
#pragma unroll
  for (int r = 0; r < 4; r++) {
    const int row = 4 * ry4 + r;
#pragma unroll
    for (int cc = 0; cc < 8; cc++)
      ob[row * DD + 8 * tx8 + cc] = o[r][cc];
  }
  if (tx8 == 0) {
#pragma unroll
    for (int r = 0; r < 4; r++)
      ob[(4 * ry4 + r) * DD + 64] = o64[r];
  }
}

extern "C" void kernel_launch(void* const* d_in, const int* in_sizes, int n_in,
                              void* d_out, int out_size, void* d_ws,
                              size_t ws_size, hipStream_t stream) {
  const float* x = (const float*)d_in[0];
  const float* Wq = (const float*)d_in[1];
  const float* Wk = (const float*)d_in[2];
  const float* Wv = (const float*)d_in[3];
  float* out = (float*)d_out;

  // Workspace: P[2048 tiles] (36.2 MB) + G[32] + T[32] (~0.57 MB each).
  float* P = (float*)d_ws;
  float* G = P + (size_t)BB * CH * TILE;
  float* Tm = G + (size_t)BB * TILE;

  k1_gram<<<BB * CH / 4, 256, 0, stream>>>(x, P);
  kred<<<BB * 5, 256, 0, stream>>>(P, G);
  k2_chain<<<BB * 9, 256, 0, stream>>>(Wq, Wk, Wv, G, Tm);
  k3_out<<<BB * CH / 4, 256, 0, stream>>>(x, Tm, out);
  (void)in_sizes; (void)n_in; (void)out_size; (void)ws_size;
}

// Round 5
// 117.167 us; speedup vs baseline: 1.0907x; 1.0358x over previous
//
#include <hip/hip_runtime.h>

#define BB 32
#define NN 2048
#define DD 65
#define HH 64
#define ST 68                // padded leading dim (16B-aligned float4 frags)
#define TILE (DD * ST)       // 4420 floats per padded 65x65 matrix
#define CC 32                // x chunks per batch (64 rows each)

__device__ __forceinline__ float4 f4add(float4 a, float4 b) {
  return make_float4(a.x + b.x, a.y + b.y, a.z + b.z, a.w + b.w);
}

// async global->LDS, 16B per lane, wave-uniform LDS base + lane*16
#define GL2LDS(g, l)                                             \
  __builtin_amdgcn_global_load_lds(                              \
      (const __attribute__((address_space(1))) void*)(g),        \
      (__attribute__((address_space(3))) void*)(l), 16, 0, 0)

// ---------------------------------------------------------------------------
// k1: partial Gram P[b][c] = (64-row x chunk)^T (chunk), 65x65 stride-68.
// 1024 blocks x 256 thr (4 blocks/CU, 4 waves/SIMD -- round-2's winning
// shape). STAGING FIX: x loaded as float4 with all 5 loads in flight
// (80 B/thread MLP) instead of 6-deep scalar b32 (24 B) -- the staging
// phase was latency-bound, not BW-bound. Scatter handles the ST padding.
// ---------------------------------------------------------------------------
__global__ __launch_bounds__(256, 4) void k1_gram(const float* __restrict__ x,
                                                  float* __restrict__ P) {
  __shared__ __align__(16) float Xl[64 * ST];
  const int t = (int)threadIdx.x;
  const int tx = t & 15, ty = t >> 4;
  const int blk = (int)blockIdx.x;
  const int b = blk >> 5, c = blk & 31;
  const float4* src4 =
      (const float4*)(x + ((size_t)b * NN + (size_t)c * 64) * DD);

  {  // f4 staging: 1040 float4, 5 slots/thread, all in flight
    float4 tmp[5];
#pragma unroll
    for (int q = 0; q < 5; q++) {
      const int i4 = t + 256 * q;
      if (i4 < 1040) tmp[q] = src4[i4];
    }
#pragma unroll
    for (int q = 0; q < 5; q++) {
      const int i4 = t + 256 * q;
      if (i4 < 1040) {
        const int f = 4 * i4;
        const float vv[4] = {tmp[q].x, tmp[q].y, tmp[q].z, tmp[q].w};
#pragma unroll
        for (int j = 0; j < 4; j++) {
          const int r = (f + j) / DD, cc = (f + j) - r * DD;
          Xl[r * ST + cc] = vv[j];
        }
      }
    }
  }
  __syncthreads();

  float g[4][4] = {};
  float g64[4] = {};
  float gcc = 0.f;
  for (int n = 0; n < 64; n++) {
    float rowf[4], colf[4];
    *(float4*)rowf = *(const float4*)&Xl[n * ST + 4 * ty];
    *(float4*)colf = *(const float4*)&Xl[n * ST + 4 * tx];
    const float x64 = Xl[n * ST + 64];  // broadcast, conflict-free
#pragma unroll
    for (int r = 0; r < 4; r++)
#pragma unroll
      for (int cc = 0; cc < 4; cc++)
        g[r][cc] = fmaf(rowf[r], colf[cc], g[r][cc]);
#pragma unroll
    for (int cc = 0; cc < 4; cc++) g64[cc] = fmaf(x64, colf[cc], g64[cc]);
    gcc = fmaf(x64, x64, gcc);
  }
  float* Pp = P + (size_t)blk * TILE;
#pragma unroll
  for (int r = 0; r < 4; r++)
    *(float4*)&Pp[(4 * ty + r) * ST + 4 * tx] = *(float4*)g[r];
  if (ty == 0) {
    *(float4*)&Pp[64 * ST + 4 * tx] = *(float4*)g64;  // G[64][j]
#pragma unroll
    for (int cc = 0; cc < 4; cc++)
      Pp[(4 * tx + cc) * ST + 64] = g64[cc];          // G[i][64] by symmetry
    if (tx == 0) Pp[64 * ST + 64] = gcc;
  }
}

// ---------------------------------------------------------------------------
// kred: G[b] = sum over 32 chunk tiles of P[b]. 160 blocks (5 per batch),
// one float4 slot per thread, 8 loads in flight + tree sum (x4 groups).
// ---------------------------------------------------------------------------
__global__ __launch_bounds__(256) void kred(const float* __restrict__ P,
                                            float* __restrict__ G) {
  const int t = (int)threadIdx.x;
  const int blk = (int)blockIdx.x;
  const int b = blk / 5, s = blk - b * 5;
  const int Q = TILE / 4;  // 1105
  const int i4 = s * 256 + t;
  if (i4 < Q) {
    const float4* Pb = (const float4*)(P + (size_t)b * CC * TILE);
    float4 acc = make_float4(0.f, 0.f, 0.f, 0.f);
#pragma unroll
    for (int grp = 0; grp < 4; grp++) {
      float4 v[8];
#pragma unroll
      for (int cc = 0; cc < 8; cc++)
        v[cc] = Pb[(size_t)(8 * grp + cc) * Q + i4];
#pragma unroll
      for (int stp = 4; stp >= 1; stp >>= 1)
#pragma unroll
        for (int cc = 0; cc < stp; cc++) v[cc] = f4add(v[cc], v[cc + stp]);
      acc = f4add(acc, v[0]);
    }
    ((float4*)(G + (size_t)b * TILE))[i4] = acc;
  }
}

// ---------------------------------------------------------------------------
// k2b: ROW-PARALLEL chain. T[i,:] = M[i,:] G Wv^T with M = Wq^T Wk.
// 288 blocks (9 row-groups x 32 batches); staging already 34-deep in
// flight -> unchanged from round 2.
// ---------------------------------------------------------------------------
__global__ __launch_bounds__(256) void k2_chain(
    const float* __restrict__ Wq, const float* __restrict__ Wk,
    const float* __restrict__ Wv, const float* __restrict__ G,
    float* __restrict__ Tm) {
  __shared__ __align__(16) float WqL[HH * ST];
  __shared__ __align__(16) float WkL[HH * ST];
  __shared__ __align__(16) float GL[TILE];
  __shared__ __align__(16) float WvT[TILE];
  __shared__ __align__(16) float Mr[8 * ST];
  __shared__ __align__(16) float Rr[8 * ST];

  const int t = (int)threadIdx.x;
  const int tx = t & 31, ty = t >> 5;
  const int blk = (int)blockIdx.x;
  const int b = blk / 9, rg = blk - b * 9;
  const int i = 8 * rg + ty;
  const bool alive = (i < DD);
  const int ic = alive ? i : 0;

  {
    float tq[17], tk[17];
#pragma unroll
    for (int q = 0; q < 17; q++) {
      const int idx = t + 256 * q;
      if (idx < HH * DD) { tq[q] = Wq[idx]; tk[q] = Wk[idx]; }
    }
#pragma unroll
    for (int q = 0; q < 17; q++) {
      const int idx = t + 256 * q;
      if (idx < HH * DD) {
        const int r = idx / DD, cc = idx - r * DD;
        WqL[r * ST + cc] = tq[q];
        WkL[r * ST + cc] = tk[q];
      }
    }
  }
  {
    const float4* Gb4 = (const float4*)(G + (size_t)b * TILE);
    float4 tG[5];
#pragma unroll
    for (int q = 0; q < 5; q++) {
      const int i4 = t + 256 * q;
      if (i4 < TILE / 4) tG[q] = Gb4[i4];
    }
#pragma unroll
    for (int q = 0; q < 5; q++) {
      const int i4 = t + 256 * q;
      if (i4 < TILE / 4) *((float4*)GL + i4) = tG[q];
    }
  }
  {
    float tv[17];
#pragma unroll
    for (int q = 0; q < 17; q++) {
      const int idx = t + 256 * q;
      if (idx < DD * DD) tv[q] = Wv[idx];
    }
#pragma unroll
    for (int q = 0; q < 17; q++) {
      const int idx = t + 256 * q;
      if (idx < DD * DD) {
        const int j = idx / DD, k = idx - j * DD;
        WvT[k * ST + j] = tv[q];
      }
    }
  }
  __syncthreads();

  {
    float m0 = 0.f, m1 = 0.f, m2 = 0.f;
    for (int h = 0; h < HH; h++) {
      const float wq = WqL[h * ST + ic];
      m0 = fmaf(wq, WkL[h * ST + tx], m0);
      m1 = fmaf(wq, WkL[h * ST + tx + 32], m1);
      m2 = fmaf(wq, WkL[h * ST + 64], m2);
    }
    if (alive) {
      Mr[ty * ST + tx] = m0;
      Mr[ty * ST + tx + 32] = m1;
      if (tx == 0) Mr[ty * ST + 64] = m2;
    }
  }
  __syncthreads();

  {
    float r0 = 0.f, r1 = 0.f, r2 = 0.f;
    for (int k = 0; k < DD; k++) {
      const float mm = Mr[ty * ST + k];
      r0 = fmaf(mm, GL[k * ST + tx], r0);
      r1 = fmaf(mm, GL[k * ST + tx + 32], r1);
      r2 = fmaf(mm, GL[k * ST + 64], r2);
    }
    if (alive) {
      Rr[ty * ST + tx] = r0;
      Rr[ty * ST + tx + 32] = r1;
      if (tx == 0) Rr[ty * ST + 64] = r2;
    }
  }
  __syncthreads();

  {
    float t0 = 0.f, t1 = 0.f, t2 = 0.f;
    for (int k = 0; k < DD; k++) {
      const float rv = Rr[ty * ST + k];
      t0 = fmaf(rv, WvT[k * ST + tx], t0);
      t1 = fmaf(rv, WvT[k * ST + tx + 32], t1);
      t2 = fmaf(rv, WvT[k * ST + 64], t2);
    }
    if (alive) {
      float* Tb = Tm + (size_t)b * TILE + (size_t)i * ST;
      Tb[tx] = t0;
      Tb[tx + 32] = t1;
      if (tx == 0) Tb[64] = t2;
    }
  }
}

// ---------------------------------------------------------------------------
// k3: out[b] = x[b] @ T[b]. Round-2 shape (1024 blocks, lb(256,4), async
// GL2LDS for Tl, LDS repack epilogue for coalesced f4 stores). STAGING FIX:
// Xl loaded as float4 with 5 loads in flight instead of 2x9 scalar b32.
// ---------------------------------------------------------------------------
__global__ __launch_bounds__(256, 4) void k3_out(const float* __restrict__ x,
                                                 const float* __restrict__ Tt,
                                                 float* __restrict__ out) {
  __shared__ __align__(16) float Tl[TILE];       // 17680 B
  __shared__ __align__(16) float Xl[64 * ST];    // 17408 B (reused as Ol)
  const int t = (int)threadIdx.x;
  const int tx = t & 15, ty = t >> 4;
  const int wid = t >> 6, lane = t & 63;
  const int blk = (int)blockIdx.x;
  const int b = blk >> 5;           // 32 blocks per batch
  const int rb = (blk & 31) * 64;
  const float4* Tg4 = (const float4*)(Tt + (size_t)b * TILE);
  const float4* src4 = (const float4*)(x + ((size_t)b * NN + rb) * DD);

  // ---- async stage T -> Tl: 1105 float4 slots, 16B/lane, fire-and-forget
#pragma unroll
  for (int q = 0; q < 4; q++) {
    const int s = q * 256 + wid * 64 + lane;          // < 1024
    GL2LDS(Tg4 + s, Tl + (size_t)(q * 256 + wid * 64) * 4);
  }
  {
    const int s = 1024 + wid * 64 + lane;             // tail: 81 slots
    if (s < TILE / 4) GL2LDS(Tg4 + s, Tl + (size_t)(1024 + wid * 64) * 4);
  }

  // ---- f4 stage x chunk -> Xl (padded): 5 loads in flight + scatter
  {
    float4 tmp[5];
#pragma unroll
    for (int q = 0; q < 5; q++) {
      const int i4 = t + 256 * q;
      if (i4 < 1040) tmp[q] = src4[i4];
    }
#pragma unroll
    for (int q = 0; q < 5; q++) {
      const int i4 = t + 256 * q;
      if (i4 < 1040) {
        const int f = 4 * i4;
        const float vv[4] = {tmp[q].x, tmp[q].y, tmp[q].z, tmp[q].w};
#pragma unroll
        for (int j = 0; j < 4; j++) {
          const int r = (f + j) / DD, cc = (f + j) - r * DD;
          Xl[r * ST + cc] = vv[j];
        }
      }
    }
  }
  __syncthreads();  // drains vmcnt -> Tl ready too

  float o[4][4] = {}, o64[4] = {};
  for (int kk = 0; kk < 64; kk += 4) {
    float xa4[4][4];  // [r][e]
    float tb4[4][4];  // [e][cc]
    float t64e[4];
#pragma unroll
    for (int r = 0; r < 4; r++)
      *(float4*)xa4[r] = *(const float4*)&Xl[(4 * ty + r) * ST + kk];
#pragma unroll
    for (int e = 0; e < 4; e++)
      *(float4*)tb4[e] = *(const float4*)&Tl[(kk + e) * ST + 4 * tx];
#pragma unroll
    for (int e = 0; e < 4; e++) t64e[e] = Tl[(kk + e) * ST + 64];
#pragma unroll
    for (int e = 0; e < 4; e++) {
#pragma unroll
      for (int r = 0; r < 4; r++)
#pragma unroll
        for (int cc = 0; cc < 4; cc++)
          o[r][cc] = fmaf(xa4[r][e], tb4[e][cc], o[r][cc]);
#pragma unroll
      for (int r = 0; r < 4; r++)
        o64[r] = fmaf(xa4[r][e], t64e[e], o64[r]);
    }
  }
  {  // k = 64 tail (unpredicated compute)
    float xs[4];
#pragma unroll
    for (int r = 0; r < 4; r++) xs[r] = Xl[(4 * ty + r) * ST + 64];
    float tb[4];
    *(float4*)tb = *(const float4*)&Tl[64 * ST + 4 * tx];
    const float t64 = Tl[64 * ST + 64];
#pragma unroll
    for (int r = 0; r < 4; r++) {
#pragma unroll
      for (int cc = 0; cc < 4; cc++)
        o[r][cc] = fmaf(xs[r], tb[cc], o[r][cc]);
      o64[r] = fmaf(xs[r], t64, o64[r]);
    }
  }

  // ---- epilogue: repack through LDS (reuse Xl) for coalesced f4 stores
  __syncthreads();  // everyone done reading Xl/Tl
  float* Ol = Xl;   // unpadded [64][65]
#pragma unroll
  for (int r = 0; r < 4; r++) {
#pragma unroll
    for (int cc = 0; cc < 4; cc++)
      Ol[(4 * ty + r) * DD + 4 * tx + cc] = o[r][cc];
  }
  if (tx == 0) {
#pragma unroll
    for (int r = 0; r < 4; r++) Ol[(4 * ty + r) * DD + 64] = o64[r];
  }
  __syncthreads();
  {
    float4* ob4 = (float4*)(out + ((size_t)b * NN + rb) * DD);  // 16B aligned
    const float4* Ol4 = (const float4*)Ol;
#pragma unroll
    for (int q = 0; q < 5; q++) {
      const int i4 = t + 256 * q;
      if (i4 < (64 * DD) / 4) ob4[i4] = Ol4[i4];
    }
  }
}

extern "C" void kernel_launch(void* const* d_in, const int* in_sizes, int n_in,
                              void* d_out, int out_size, void* d_ws,
                              size_t ws_size, hipStream_t stream) {
  const float* x = (const float*)d_in[0];
  const float* Wq = (const float*)d_in[1];
  const float* Wk = (const float*)d_in[2];
  const float* Wv = (const float*)d_in[3];
  float* out = (float*)d_out;

  // Workspace: P[B*32 tiles] (18.1 MB) + G[B tiles] + T[B tiles] (~0.6 MB ea).
  float* P = (float*)d_ws;
  float* G = P + (size_t)BB * CC * TILE;
  float* Tm = G + (size_t)BB * TILE;

  k1_gram<<<BB * CC, 256, 0, stream>>>(x, P);
  kred<<<BB * 5, 256, 0, stream>>>(P, G);
  k2_chain<<<BB * 9, 256, 0, stream>>>(Wq, Wk, Wv, G, Tm);
  k3_out<<<BB * CC, 256, 0, stream>>>(x, Tm, out);
  (void)in_sizes; (void)n_in; (void)out_size; (void)ws_size;
}